// Round 9
// baseline (44.188 us; speedup 1.0000x reference)
//
#include <hip/hip_runtime.h>
#include <hip/hip_bf16.h>

#define BB 8
#define NN 2048
#define FF 128

typedef __bf16 bf16x8 __attribute__((ext_vector_type(8)));
typedef float f32x4 __attribute__((ext_vector_type(4)));
typedef float f32x16 __attribute__((ext_vector_type(16)));

__device__ __forceinline__ void gload_lds16(const void* g, void* l) {
    __builtin_amdgcn_global_load_lds(
        (const __attribute__((address_space(1))) unsigned int*)g,
        (__attribute__((address_space(3))) unsigned int*)l, 16, 0, 0);
}

// ---------------------------------------------------------------------------
// Kernel A: Wh = h @ W (bf16 MFMA), src/dst rowvecs, fragB packed in
// 32x32x16 MFMA B-fragment order (unchanged — passed refcheck):
//   fragB[((b*128+jt)*4+ft)*64 + lane][e] =
//     Wh[jt*16 + (lane>>5)*8 + e][ft*32 + (lane&31)]
// ---------------------------------------------------------------------------
__global__ __launch_bounds__(256) void wh_kernel(
    const float* __restrict__ h, const float* __restrict__ W,
    const float* __restrict__ a, __bf16* __restrict__ fragB,
    float* __restrict__ srcg, float* __restrict__ dstg)
{
    __shared__ float  s_h[32][132];
    __shared__ __bf16 s_wh[32][132];
    __shared__ float  s_s[2][32];
    __shared__ float  s_d[2][32];

    const int bid = blockIdx.x;
    const int b   = bid >> 6;
    const int J   = bid & 63;
    const int r0  = J * 32;
    const int t   = threadIdx.x;
    const int w   = t >> 6;
    const int l   = t & 63;
    const int itile = w & 1;
    const int fh    = w >> 1;
    const int g     = l >> 4;
    const int c16   = l & 15;

#pragma unroll
    for (int i = 0; i < 4; ++i) {
        const int idx = t + i * 256;
        const int r   = idx >> 5;
        const int c4  = idx & 31;
        *(f32x4*)&s_h[r][c4 * 4] =
            *(const f32x4*)(h + (size_t)(b * NN + r0 + r) * FF + c4 * 4);
    }
    __syncthreads();

    const float* hrow = &s_h[itile * 16 + c16][0];
    f32x4 acc[4] = {};

#pragma unroll
    for (int kt = 0; kt < 4; ++kt) {
        const int k0 = kt * 32 + g * 8;
        f32x4 h0 = *(const f32x4*)(hrow + k0);
        f32x4 h1 = *(const f32x4*)(hrow + k0 + 4);
        bf16x8 af;
        af[0]=(__bf16)h0[0]; af[1]=(__bf16)h0[1]; af[2]=(__bf16)h0[2]; af[3]=(__bf16)h0[3];
        af[4]=(__bf16)h1[0]; af[5]=(__bf16)h1[1]; af[6]=(__bf16)h1[2]; af[7]=(__bf16)h1[3];
#pragma unroll
        for (int ft = 0; ft < 4; ++ft) {
            const int c = (fh * 4 + ft) * 16 + c16;
            bf16x8 bf;
#pragma unroll
            for (int e = 0; e < 8; ++e) bf[e] = (__bf16)W[(k0 + e) * FF + c];
            acc[ft] = __builtin_amdgcn_mfma_f32_16x16x32_bf16(af, bf, acc[ft], 0, 0, 0);
        }
    }

    float a1v[4], a2v[4];
#pragma unroll
    for (int ft = 0; ft < 4; ++ft) {
        const int c = (fh * 4 + ft) * 16 + c16;
        a1v[ft] = a[c];
        a2v[ft] = a[FF + c];
    }
#pragma unroll
    for (int r = 0; r < 4; ++r) {
        float s = 0.f, d2 = 0.f;
#pragma unroll
        for (int ft = 0; ft < 4; ++ft) {
            s  += acc[ft][r] * a1v[ft];
            d2 += acc[ft][r] * a2v[ft];
        }
#pragma unroll
        for (int m = 1; m <= 8; m <<= 1) {
            s  += __shfl_xor(s,  m);
            d2 += __shfl_xor(d2, m);
        }
        if (c16 == 0) {
            s_s[fh][itile * 16 + g * 4 + r] = s;
            s_d[fh][itile * 16 + g * 4 + r] = d2;
        }
    }

#pragma unroll
    for (int ft = 0; ft < 4; ++ft)
#pragma unroll
        for (int r = 0; r < 4; ++r)
            s_wh[itile * 16 + g * 4 + r][(fh * 4 + ft) * 16 + c16] = (__bf16)acc[ft][r];

    __syncthreads();

#pragma unroll
    for (int e2 = 0; e2 < 2; ++e2) {
        const int ent  = t + e2 * 256;
        const int tile = ent >> 6;
        const int jl   = tile >> 2;
        const int ft   = tile & 3;
        const int lE   = ent & 63;
        const int rowE = jl * 16 + (lE >> 5) * 8;
        const int colE = ft * 32 + (lE & 31);
        bf16x8 v;
#pragma unroll
        for (int ee = 0; ee < 8; ++ee) v[ee] = s_wh[rowE + ee][colE];
        *(bf16x8*)(fragB + (((size_t)(b * 128 + J * 2 + jl) * 4 + ft) * 64 + lE) * 8) = v;
    }

    if (t < 32) {
        srcg[b * NN + r0 + t] = s_s[0][t] + s_s[1][t];
        dstg[b * NN + r0 + t] = s_d[0][t] + s_d[1][t];
    }
}

// ---------------------------------------------------------------------------
// Kernel B v9: frag in REGISTERS (asm global_load_dwordx4, distance 3),
// adj via LDS DMA (distance 3), uniform-age vmcnt ledger.
// 4 waves = 4 j-quarters, 32 steps x 16 j/wave, M=32 mfma_f32_32x32x16_bf16.
// Per step: issue F(kt+3)[4 reg loads] + A(kt+3)[2 DMA]; s_waitcnt vmcnt(18)
// retires exactly {F(kt), A(kt)} (both age 3 steps); sched_barrier(0) fences
// MFMA hoisting past the wait (rule 18). Zero inner barriers.
// ---------------------------------------------------------------------------
__global__ __launch_bounds__(256, 2) void attn_kernel(
    const int* __restrict__ adj, const __bf16* __restrict__ fragB,
    const float* __restrict__ srcg, const float* __restrict__ dstg,
    float* __restrict__ out)
{
    __shared__ char s_all[41472];
    // [0,32768):      adj 4 slots x 2048 per wave (q*8192)
    // [32768,40960):  dst 2048 per wave
    // [40960,41472):  s_ps
    // tail combine reuses [0,34816)

    const int bid0 = blockIdx.x;
    const int bid  = (bid0 & 7) * 64 + (bid0 >> 3);   // bijective XCD swizzle
    const int b    = bid >> 6;
    const int I0   = (bid & 63) * 32;
    const int t    = threadIdx.x;
    const int q    = t >> 6;                  // wave = j-quarter
    const int l    = t & 63;
    const int r31  = l & 31;
    const int hi   = l >> 5;

    char* awave = s_all + q * 8192;
    char* dstw  = s_all + 32768 + q * 2048;
    float* s_ps = (float*)(s_all + 40960);

    // ---- plain src load, fully drained BEFORE the DMA ledger starts ----
    const float sv = srcg[b * NN + I0 + r31];
    asm volatile("s_waitcnt vmcnt(0) lgkmcnt(0)" ::: "memory");

    const char* aSrc = (const char*)adj
        + ((size_t)(b * NN + I0 + r31) * NN + q * 512) * 4 + hi * 32;
    const char* fBase = (const char*)fragB
        + (size_t)(b * 128 + q * 32) * 4096 + (size_t)l * 16;
    const char* dSrc = (const char*)(dstg + (size_t)b * NN + q * 512) + l * 16;

#define ISSUE_F(ki_, B0_, B1_, B2_, B3_) {                                    \
        const char* pf_ = fBase + (size_t)(ki_) * 4096;                       \
        asm volatile("global_load_dwordx4 %0, %1, off"                        \
                     : "=&v"(B0_) : "v"(pf_));                                \
        asm volatile("global_load_dwordx4 %0, %1, off offset:1024"            \
                     : "=&v"(B1_) : "v"(pf_));                                \
        asm volatile("global_load_dwordx4 %0, %1, off offset:2048"            \
                     : "=&v"(B2_) : "v"(pf_));                                \
        asm volatile("global_load_dwordx4 %0, %1, off offset:3072"            \
                     : "=&v"(B3_) : "v"(pf_)); }
#define ISSUE_A(ki_) {                                                        \
        const char* pa_ = aSrc + (size_t)(ki_) * 64;                          \
        gload_lds16(pa_,      awave + ((ki_) & 3) * 2048 + l * 16);           \
        gload_lds16(pa_ + 16, awave + ((ki_) & 3) * 2048 + 1024 + l * 16); }

    bf16x8 fA0, fA1, fA2, fA3, fB0, fB1, fB2, fB3;
    bf16x8 fC0, fC1, fC2, fC3, fD0, fD1, fD2, fD3;
    f32x16 acc0 = {}, acc1 = {}, acc2 = {}, acc3 = {};
    float psum = 0.f;

    // prologue ledger (mirrors steady state of steps -3..-1):
    // dst(2), then F(0),A(0), F(1),A(1), F(2),A(2)  -> 20 outstanding
    gload_lds16(dSrc,        dstw + l * 16);
    gload_lds16(dSrc + 1024, dstw + 1024 + l * 16);
    ISSUE_F(0, fA0, fA1, fA2, fA3);  ISSUE_A(0);
    ISSUE_F(1, fB0, fB1, fB2, fB3);  ISSUE_A(1);
    ISSUE_F(2, fC0, fC1, fC2, fC3);  ISSUE_A(2);

#define STEP(kt_, C0_, C1_, C2_, C3_, I0_, I1_, I2_, I3_) {                   \
        const int kX_ = ((kt_) + 3 < 32) ? (kt_) + 3 : 31;                    \
        ISSUE_F(kX_, I0_, I1_, I2_, I3_);                                     \
        ISSUE_A(kX_);                                                         \
        asm volatile("s_waitcnt vmcnt(18)" ::: "memory");                     \
        __builtin_amdgcn_sched_barrier(0);                                    \
        const char* asl_ = awave + ((kt_) & 3) * 2048 + l * 16;               \
        const int4 A0_ = *(const int4*)(asl_);                                \
        const int4 A1_ = *(const int4*)(asl_ + 1024);                         \
        const f32x4 d0_ = *(const f32x4*)(dstw + (kt_) * 64 + hi * 32);       \
        const f32x4 d1_ = *(const f32x4*)(dstw + (kt_) * 64 + hi * 32 + 16);  \
        const int   am_[8] = {A0_.x, A0_.y, A0_.z, A0_.w,                     \
                              A1_.x, A1_.y, A1_.z, A1_.w};                    \
        const float dv_[8] = {d0_[0], d0_[1], d0_[2], d0_[3],                 \
                              d1_[0], d1_[1], d1_[2], d1_[3]};                \
        bf16x8 af_;                                                           \
        _Pragma("unroll")                                                     \
        for (int e = 0; e < 8; ++e) {                                         \
            float x = sv + dv_[e];                                            \
            x = fmaxf(x, 0.2f * x);                                           \
            float p = __expf(x);                                              \
            p = (am_[e] > 0) ? p : 0.f;                                       \
            psum += p;                                                        \
            af_[e] = (__bf16)p;                                               \
        }                                                                     \
        acc0 = __builtin_amdgcn_mfma_f32_32x32x16_bf16(af_, C0_, acc0, 0, 0, 0); \
        acc1 = __builtin_amdgcn_mfma_f32_32x32x16_bf16(af_, C1_, acc1, 0, 0, 0); \
        acc2 = __builtin_amdgcn_mfma_f32_32x32x16_bf16(af_, C2_, acc2, 0, 0, 0); \
        acc3 = __builtin_amdgcn_mfma_f32_32x32x16_bf16(af_, C3_, acc3, 0, 0, 0); }

    for (int kt4 = 0; kt4 < 32; kt4 += 4) {
        STEP(kt4 + 0, fA0, fA1, fA2, fA3, fD0, fD1, fD2, fD3);
        STEP(kt4 + 1, fB0, fB1, fB2, fB3, fA0, fA1, fA2, fA3);
        STEP(kt4 + 2, fC0, fC1, fC2, fC3, fB0, fB1, fB2, fB3);
        STEP(kt4 + 3, fD0, fD1, fD2, fD3, fC0, fC1, fC2, fC3);
    }
#undef STEP
#undef ISSUE_F
#undef ISSUE_A

    asm volatile("s_waitcnt vmcnt(0) lgkmcnt(0)" ::: "memory");  // drain dummies

    // denom partial: lanes l and l^32 cover the same row, disjoint j
    psum += __shfl_xor(psum, 32);
    if (l < 32) s_ps[q * 32 + l] = psum;

    // ---- 4-way j-partial combine in two rounds (reuse pipe LDS) ----
    float* comb = (float*)s_all;              // [(p*2+f)*64+l]*17, 34816 B
    f32x16 tot;

    __syncthreads();
    {   // round 0: ft tiles 0,1
        float* c0 = comb + ((q * 2 + 0) * 64 + l) * 17;
        float* c1 = comb + ((q * 2 + 1) * 64 + l) * 17;
#pragma unroll
        for (int r = 0; r < 16; ++r) { c0[r] = acc0[r]; c1[r] = acc1[r]; }
    }
    __syncthreads();
    if (q < 2) {
#pragma unroll
        for (int r = 0; r < 16; ++r)
            tot[r] = comb[((0 * 2 + q) * 64 + l) * 17 + r]
                   + comb[((1 * 2 + q) * 64 + l) * 17 + r]
                   + comb[((2 * 2 + q) * 64 + l) * 17 + r]
                   + comb[((3 * 2 + q) * 64 + l) * 17 + r];
    }
    __syncthreads();
    {   // round 1: ft tiles 2,3
        float* c0 = comb + ((q * 2 + 0) * 64 + l) * 17;
        float* c1 = comb + ((q * 2 + 1) * 64 + l) * 17;
#pragma unroll
        for (int r = 0; r < 16; ++r) { c0[r] = acc2[r]; c1[r] = acc3[r]; }
    }
    __syncthreads();
    if (q >= 2) {
        const int f2 = q - 2;
#pragma unroll
        for (int r = 0; r < 16; ++r)
            tot[r] = comb[((0 * 2 + f2) * 64 + l) * 17 + r]
                   + comb[((1 * 2 + f2) * 64 + l) * 17 + r]
                   + comb[((2 * 2 + f2) * 64 + l) * 17 + r]
                   + comb[((3 * 2 + f2) * 64 + l) * 17 + r];
    }

    const float dtot = s_ps[0 * 32 + r31] + s_ps[1 * 32 + r31]
                     + s_ps[2 * 32 + r31] + s_ps[3 * 32 + r31];
    const float rin  = 1.f / dtot;

    // C layout (32x32): col = l&31, row = (r&3) + 8*(r>>2) + 4*hi
#pragma unroll
    for (int r = 0; r < 16; ++r) {
        const int row  = (r & 3) + 8 * (r >> 2) + 4 * hi;
        const float dv2 = __shfl(rin, row);
        out[(size_t)(b * NN + I0 + row) * FF + q * 32 + r31] = tot[r] * dv2;
    }
}

// ---------------------------------------------------------------------------
extern "C" void kernel_launch(void* const* d_in, const int* in_sizes, int n_in,
                              void* d_out, int out_size, void* d_ws, size_t ws_size,
                              hipStream_t stream)
{
    const float* h   = (const float*)d_in[0];
    const int*   adj = (const int*)d_in[1];
    const float* W   = (const float*)d_in[2];
    const float* a   = (const float*)d_in[3];
    float* out = (float*)d_out;

    char* ws = (char*)d_ws;
    __bf16* fragB = (__bf16*)ws;                              // 4 MiB
    float*  srcg  = (float*)(ws + (4 << 20));                 // 64 KiB
    float*  dstg  = (float*)(ws + (4 << 20) + (64 << 10));    // 64 KiB

    wh_kernel<<<512, 256, 0, stream>>>(h, W, a, fragB, srcg, dstg);
    attn_kernel<<<512, 256, 0, stream>>>(adj, fragB, srcg, dstg, out);
}